// Round 1
// baseline (195.864 us; speedup 1.0000x reference)
//
#include <hip/hip_runtime.h>

typedef __attribute__((ext_vector_type(4))) float f32x4;
typedef __attribute__((ext_vector_type(8))) short s16x8;

#define DEV __device__ __forceinline__

namespace {
constexpr int CH = 128;    // C == D
constexpr int TDIM = 512;  // T
constexpr float INV_ROWS = 1.0f / 65536.0f;  // N*T
constexpr float EPS = 1e-5f;

DEV unsigned short f2bf(float f) {
  unsigned int u = __float_as_uint(f);
  u = (u + 0x7FFFu + ((u >> 16) & 1u)) >> 16;  // RNE
  return (unsigned short)u;
}
DEV float bf2f(unsigned short s) { return __uint_as_float(((unsigned int)s) << 16); }

// gathered/masked tile, bf16, [v][t][c] with XOR swizzle on c (16B-slot spread)
DEV int xg_idx(int v, int t, int c) { return v * 4096 + t * 128 + (c ^ ((t & 7) << 3)); }
// raw x tile, bf16, [c][t][v0..3] with XOR swizzle on t*4
DEV int raw_idx(int c, int t) { return c * 128 + ((t * 4) ^ (((c >> 1) & 7) << 2)); }
}  // namespace

// PHASE 1: compute o = (gathered x * mask) @ W per node-plane, accumulate per-column
//          sum / sumsq into ws (no stores of o).
// PHASE 2: recompute o, apply BN affine (precomputed scale/shift per output column,
//          gathered through shift_out register-locally), add residual, ReLU, store.
template <int PHASE>
__global__ __launch_bounds__(512, 2) void gcn_fused(
    const float* __restrict__ x, const float* __restrict__ W,
    const float* __restrict__ FM, const int* __restrict__ shin,
    const int* __restrict__ shout, const float* __restrict__ tab,
    float* __restrict__ sums, float* __restrict__ out) {
  __shared__ __align__(16) unsigned short xg[4 * 32 * 128];   // 32 KB
  __shared__ __align__(16) unsigned short raw[128 * 32 * 4];  // 32 KB

  const int tid = threadIdx.x;
  const int lane = tid & 63;
  const int w = tid >> 6;   // 8 waves
  const int dq = w >> 1;    // d-quarter: 32 d's per wave
  const int th = w & 1;     // t-half of tile (16 t)
  const int dbase = dq * 32;
  const int g4 = lane >> 4;  // 0..3
  const int l16 = lane & 15;

  const int bid = blockIdx.x;          // 512 blocks
  const int n = bid >> 2;              // batch index
  const int tblk = (bid & 3) * 128;    // 128 t per block, 4 tiles of 32

  // staging thread mapping: fixed channel pair (c0,c1), t = tlow + 8*p
  const int tlow = tid & 7;
  const int q = (tid >> 3) & 63;
  const int c0 = 2 * q;
  const int c1 = c0 + 1;

  // per-thread gather constants (shift preserves channel: src = sv*128 + c)
  int svA[4], svB[4];
  float mA[4], mB[4];
#pragma unroll
  for (int v = 0; v < 4; ++v) {
    svA[v] = (shin[v * CH + c0] >> 7) & 3;
    svB[v] = (shin[v * CH + c1] >> 7) & 3;
    mA[v] = tanhf(FM[v * CH + c0]) + 1.0f;
    mB[v] = tanhf(FM[v * CH + c1]) + 1.0f;
  }

  // W^T fragments in registers: A-operand rows d = dbase+df*16+l16, k = kk*32+8*g4+e
  s16x8 wt[2][4];
#pragma unroll
  for (int df = 0; df < 2; ++df) {
#pragma unroll
    for (int kk = 0; kk < 4; ++kk) {
      s16x8 f;
#pragma unroll
      for (int e = 0; e < 8; ++e) {
        int c = kk * 32 + g4 * 8 + e;
        int d = dbase + df * 16 + l16;
        f[e] = (short)f2bf(W[c * CH + d]);
      }
      wt[df][kk] = f;
    }
  }

  // phase-2 epilogue constants (per-lane d is tile-invariant)
  unsigned int svo[2][4];
  unsigned int ss[2][4][4];
  if (PHASE == 2) {
#pragma unroll
    for (int df = 0; df < 2; ++df) {
#pragma unroll
      for (int r = 0; r < 4; ++r) {
        int d = dbase + df * 16 + g4 * 4 + r;
        unsigned int pk = 0;
#pragma unroll
        for (int v = 0; v < 4; ++v) {
          int j = v * CH + d;
          pk |= (unsigned int)((shout[j] >> 7) & 3) << (2 * v);
          float sc = tab[2 * j];
          float sh = tab[2 * j + 1];
          ss[df][r][v] = (unsigned int)f2bf(sc) | ((unsigned int)f2bf(sh) << 16);
        }
        svo[df][r] = pk;
      }
    }
  }

  float s1[4][2][4], s2a[4][2][4];
  if (PHASE == 1) {
#pragma unroll
    for (int vo = 0; vo < 4; ++vo)
#pragma unroll
      for (int df = 0; df < 2; ++df)
#pragma unroll
        for (int r = 0; r < 4; ++r) {
          s1[vo][df][r] = 0.f;
          s2a[vo][df][r] = 0.f;
        }
  }

  const f32x4* xf4 = (const f32x4*)x;
  f32x4 pa[4], pb[4];
  {  // prologue: prefetch tile 0
    int tg = tblk + tlow;
#pragma unroll
    for (int p = 0; p < 4; ++p) {
      pa[p] = xf4[(n * CH + c0) * TDIM + tg + p * 8];
      pb[p] = xf4[(n * CH + c1) * TDIM + tg + p * 8];
    }
  }

  const int tloc = th * 16 + l16;

  for (int tile = 0; tile < 4; ++tile) {
    // ---- stage registers -> LDS (gather across nodes + mask, bf16) ----
#pragma unroll
    for (int p = 0; p < 4; ++p) {
      int t = tlow + p * 8;
      if (PHASE == 2) {  // raw copy for residual
        uint2 u;
        u.x = (unsigned int)f2bf(pa[p][0]) | ((unsigned int)f2bf(pa[p][1]) << 16);
        u.y = (unsigned int)f2bf(pa[p][2]) | ((unsigned int)f2bf(pa[p][3]) << 16);
        *(uint2*)&raw[raw_idx(c0, t)] = u;
        u.x = (unsigned int)f2bf(pb[p][0]) | ((unsigned int)f2bf(pb[p][1]) << 16);
        u.y = (unsigned int)f2bf(pb[p][2]) | ((unsigned int)f2bf(pb[p][3]) << 16);
        *(uint2*)&raw[raw_idx(c1, t)] = u;
      }
#pragma unroll
      for (int v = 0; v < 4; ++v) {
        float a = pa[p][0];
        a = (svA[v] == 1) ? pa[p][1] : a;
        a = (svA[v] == 2) ? pa[p][2] : a;
        a = (svA[v] == 3) ? pa[p][3] : a;
        a *= mA[v];
        float b = pb[p][0];
        b = (svB[v] == 1) ? pb[p][1] : b;
        b = (svB[v] == 2) ? pb[p][2] : b;
        b = (svB[v] == 3) ? pb[p][3] : b;
        b *= mB[v];
        unsigned int pk = (unsigned int)f2bf(a) | ((unsigned int)f2bf(b) << 16);
        *(unsigned int*)&xg[xg_idx(v, t, c0)] = pk;
      }
    }
    // prefetch next tile (loads stay in flight across compute)
    if (tile < 3) {
      int tg = tblk + (tile + 1) * 32 + tlow;
#pragma unroll
      for (int p = 0; p < 4; ++p) {
        pa[p] = xf4[(n * CH + c0) * TDIM + tg + p * 8];
        pb[p] = xf4[(n * CH + c1) * TDIM + tg + p * 8];
      }
    }
    __syncthreads();

    // ---- MFMA: D[d][t] = sum_c W[c][d] * xg[vo][t][c] ----
    f32x4 acc[4][2];
    f32x4 z4 = {0.f, 0.f, 0.f, 0.f};
#pragma unroll
    for (int vo = 0; vo < 4; ++vo)
#pragma unroll
      for (int df = 0; df < 2; ++df) acc[vo][df] = z4;

#pragma unroll
    for (int vo = 0; vo < 4; ++vo) {
      s16x8 bfr[4];
#pragma unroll
      for (int kk = 0; kk < 4; ++kk)
        bfr[kk] = *(const s16x8*)&xg[xg_idx(vo, tloc, kk * 32 + g4 * 8)];
#pragma unroll
      for (int df = 0; df < 2; ++df)
#pragma unroll
        for (int kk = 0; kk < 4; ++kk)
          acc[vo][df] = __builtin_amdgcn_mfma_f32_16x16x32_bf16(
              wt[df][kk], bfr[kk], acc[vo][df], 0, 0, 0);
    }

    if (PHASE == 1) {
#pragma unroll
      for (int vo = 0; vo < 4; ++vo)
#pragma unroll
        for (int df = 0; df < 2; ++df)
#pragma unroll
          for (int r = 0; r < 4; ++r) {
            float v = acc[vo][df][r];
            s1[vo][df][r] += v;
            s2a[vo][df][r] += v * v;
          }
    } else {
      // ---- epilogue: shift_out gather (register select) + BN + residual + ReLU ----
      const int tg = tblk + tile * 32 + tloc;
#pragma unroll
      for (int df = 0; df < 2; ++df) {
#pragma unroll
        for (int r = 0; r < 4; ++r) {
          int d = dbase + df * 16 + g4 * 4 + r;
          uint2 rv = *(const uint2*)&raw[raw_idx(d, tloc)];
          unsigned int pk = svo[df][r];
          f32x4 o;
#pragma unroll
          for (int v = 0; v < 4; ++v) {
            int sv = (pk >> (2 * v)) & 3;
            float ov = acc[0][df][r];
            ov = (sv == 1) ? acc[1][df][r] : ov;
            ov = (sv == 2) ? acc[2][df][r] : ov;
            ov = (sv == 3) ? acc[3][df][r] : ov;
            unsigned int sspk = ss[df][r][v];
            float scale = bf2f((unsigned short)(sspk & 0xFFFFu));
            float shiftv = bf2f((unsigned short)(sspk >> 16));
            unsigned int rw = (v < 2) ? rv.x : rv.y;
            float res = bf2f((unsigned short)((v & 1) ? (rw >> 16) : (rw & 0xFFFFu)));
            float y = fmaf(ov, scale, shiftv) + res;
            o[v] = fmaxf(y, 0.f);
          }
          *(f32x4*)&out[(((n * CH + d) * TDIM) + tg) * 4] = o;
        }
      }
    }
    __syncthreads();
  }

  if (PHASE == 1) {
    // reduce over the 16 t-lanes, then global atomics (one per column instance)
#pragma unroll
    for (int vo = 0; vo < 4; ++vo) {
#pragma unroll
      for (int df = 0; df < 2; ++df) {
#pragma unroll
        for (int r = 0; r < 4; ++r) {
          float a = s1[vo][df][r];
          float b = s2a[vo][df][r];
#pragma unroll
          for (int off = 1; off < 16; off <<= 1) {
            a += __shfl_xor(a, off, 64);
            b += __shfl_xor(b, off, 64);
          }
          if (l16 == 0) {
            int d = dbase + df * 16 + g4 * 4 + r;
            atomicAdd(&sums[vo * CH + d], a);
            atomicAdd(&sums[512 + vo * CH + d], b);
          }
        }
      }
    }
  }
}

// mean/rstd per pre-shift column, then per-output-column affine via shift_out.
// (Linear_bias cancels exactly under training-mode BN -> omitted.)
__global__ void gcn_finalize(const float* __restrict__ sums,
                             const int* __restrict__ shout,
                             const float* __restrict__ gamma,
                             const float* __restrict__ beta,
                             float* __restrict__ tab) {
  __shared__ float mean_s[512];
  __shared__ float rstd_s[512];
  int j = threadIdx.x;
  float m = sums[j] * INV_ROWS;
  float v = sums[512 + j] * INV_ROWS - m * m;
  mean_s[j] = m;
  rstd_s[j] = rsqrtf(v + EPS);
  __syncthreads();
  int so = shout[j];
  float sc = rstd_s[so] * gamma[j];
  float sh = beta[j] - mean_s[so] * sc;
  tab[2 * j] = sc;
  tab[2 * j + 1] = sh;
}

extern "C" void kernel_launch(void* const* d_in, const int* in_sizes, int n_in,
                              void* d_out, int out_size, void* d_ws, size_t ws_size,
                              hipStream_t stream) {
  const float* x = (const float*)d_in[0];
  const float* W = (const float*)d_in[1];
  // d_in[2] = Linear_bias: cancels in training-mode BatchNorm, unused
  const float* FM = (const float*)d_in[3];
  const float* gamma = (const float*)d_in[4];
  const float* beta = (const float*)d_in[5];
  const int* shin = (const int*)d_in[6];
  const int* shout = (const int*)d_in[7];
  float* out = (float*)d_out;

  float* sums = (float*)d_ws;            // [0,1024): S, S2
  float* tab = (float*)d_ws + 1024;      // [1024,2048): float2 scale/shift per column

  hipMemsetAsync(d_ws, 0, 1024 * sizeof(float), stream);
  gcn_fused<1><<<dim3(512), dim3(512), 0, stream>>>(x, W, FM, shin, shout, tab, sums, out);
  gcn_finalize<<<dim3(1), dim3(512), 0, stream>>>(sums, shout, gamma, beta, tab);
  gcn_fused<2><<<dim3(512), dim3(512), 0, stream>>>(x, W, FM, shin, shout, tab, sums, out);
}